// Round 15
// baseline (35.010 us; speedup 1.0000x reference)
//
#include <hip/hip_runtime.h>
#include <math.h>

#define PI_F 3.14159265358979323846f
typedef float floatx4 __attribute__((ext_vector_type(4)));

// ---- DPP reduction ladders (HW-validated R7/R8/R11/R13/R14) ----
template <int CTRL>
__device__ __forceinline__ float dpp_addf(float v) {
  int p = __builtin_amdgcn_update_dpp(0, __float_as_int(v), CTRL, 0xF, 0xF, true);
  return v + __int_as_float(p);
}
__device__ __forceinline__ float red8(float v) {
  v = dpp_addf<0xB1>(v);
  v = dpp_addf<0x4E>(v);
  v = dpp_addf<0x104>(v);   // row_shl:4
  return v;
}
__device__ __forceinline__ float red16(float v) {
  v = dpp_addf<0xB1>(v);    // quad_perm xor1
  v = dpp_addf<0x4E>(v);    // quad_perm xor2
  v = dpp_addf<0x124>(v);   // row_ror:4
  v = dpp_addf<0x128>(v);   // row_ror:8
  return v;
}
// 64-lane sum: DPP for the 16-lane part, shfl for the 16/32 crossings.
__device__ __forceinline__ float red64(float v) {
  v = red16(v);
  v += __shfl_xor(v, 16);
  v += __shfl_xor(v, 32);
  return v;
}

// Kernel 1: Zernike pooling, register-resident (NO LDS staging).
// (= round-13/14 best; unchanged)
__global__ __launch_bounds__(256) void zpool_kernel(const float* __restrict__ x,
                                                    float* __restrict__ pooled) {
  const int blk = blockIdx.x;              // 0..3071
  const int b = blk / 3;
  const int rank = blk - b * 3;
  const floatx4* __restrict__ src4 =
      reinterpret_cast<const floatx4*>(x) + (size_t)b * 6144 + rank * 8;

  const int t = threadIdx.x;
  const int lane = t & 63;
  const int w = t >> 6;                    // wave 0..3
  const int cq = lane >> 3;                // channel quad 0..7 (8 contiguous lanes)
  const int s = lane & 7;                  // pixel-slot within group
  const int xcol = (8 * w + s) & 15;
  const int hoff = w >> 1;                 // 0 or 1
  const float X = -1.0f + (float)xcol * (2.0f / 15.0f);   // thread-constant

  __shared__ float p1[4][8][12];
  __shared__ float cxy[8][8];
  __shared__ float p2[4][8][40];

  floatx4 f[8];
#pragma unroll
  for (int i = 0; i < 8; ++i)
    f[i] = src4[(32 * i + 8 * w + s) * 24 + cq];

  // ---- Pass 1: centroid sums ----
  floatx4 s0v = {0, 0, 0, 0}, syv = {0, 0, 0, 0};
#pragma unroll
  for (int i = 0; i < 8; ++i) {
    const float Y = -1.0f + (float)(2 * i + hoff) * (2.0f / 15.0f);
    s0v += f[i];
    syv += f[i] * Y;
  }
  floatx4 sxv = s0v * X;
#pragma unroll
  for (int c = 0; c < 4; ++c) {
    s0v[c] = red8(s0v[c]);
    sxv[c] = red8(sxv[c]);
    syv[c] = red8(syv[c]);
  }
  if (s == 0) {
#pragma unroll
    for (int c = 0; c < 4; ++c) {
      p1[w][cq][c] = s0v[c];
      p1[w][cq][4 + c] = sxv[c];
      p1[w][cq][8 + c] = syv[c];
    }
  }
  __syncthreads();
  if (t < 8) {
#pragma unroll
    for (int c = 0; c < 4; ++c) {
      float S0 = 0.0f, SX = 0.0f, SY = 0.0f;
#pragma unroll
      for (int w2 = 0; w2 < 4; ++w2) {
        S0 += p1[w2][t][c];
        SX += p1[w2][t][4 + c];
        SY += p1[w2][t][8 + c];
      }
      const float inv = 1.0f / (S0 + 1e-6f);
      cxy[t][c] = SX * inv;
      cxy[t][4 + c] = SY * inv;
    }
  }
  __syncthreads();
  floatx4 cx, cy;
#pragma unroll
  for (int c = 0; c < 4; ++c) { cx[c] = cxy[cq][c]; cy[c] = cxy[cq][4 + c]; }

  const floatx4 Xs = X - cx;
  const floatx4 Xs2 = Xs * Xs;
  const floatx4 Xs3 = Xs2 * Xs;
  const floatx4 lim = 1.0f - Xs2;          // mask: Ys^2 <= 1 - Xs^2

  // ---- Pass 2: moments m_j = sum g * Ys^j ----
  floatx4 m0 = {0,0,0,0}, m1 = {0,0,0,0}, m2 = {0,0,0,0}, m3 = {0,0,0,0};
#pragma unroll
  for (int i = 0; i < 8; ++i) {
    const float Y = -1.0f + (float)(2 * i + hoff) * (2.0f / 15.0f);
    const floatx4 Ys = Y - cy;
    const floatx4 Ys2 = Ys * Ys;
    floatx4 g;
#pragma unroll
    for (int c = 0; c < 4; ++c) g[c] = (Ys2[c] <= lim[c]) ? f[i][c] : 0.0f;
    const floatx4 gy = g * Ys;
    m0 += g;
    m1 += gy;
    m2 += gy * Ys;
    m3 += gy * Ys2;
  }

  floatx4 S[10];
  S[0] = m0;        S[1] = Xs * m0;  S[2] = Xs2 * m0; S[3] = Xs3 * m0;
  S[4] = m1;        S[5] = Xs * m1;  S[6] = Xs2 * m1;
  S[7] = m2;        S[8] = Xs * m2;  S[9] = m3;
#pragma unroll
  for (int v = 0; v < 10; ++v)
#pragma unroll
    for (int c = 0; c < 4; ++c) S[v][c] = red8(S[v][c]);

  if (s == 0) {
#pragma unroll
    for (int v = 0; v < 10; ++v)
#pragma unroll
      for (int c = 0; c < 4; ++c) p2[w][cq][v * 4 + c] = S[v][c];
  }
  __syncthreads();

  if (t < 32) {
    const int fcq = t >> 2, comp = t & 3;
    float T[10];
#pragma unroll
    for (int v = 0; v < 10; ++v) {
      float acc = 0.0f;
#pragma unroll
      for (int w2 = 0; w2 < 4; ++w2) acc += p2[w2][fcq][v * 4 + comp];
      T[v] = acc;
    }
    const float S00 = T[0], S10 = T[1], S20 = T[2], S30 = T[3];
    const float S01 = T[4], S11 = T[5], S21 = T[6];
    const float S02 = T[7], S12 = T[8], S03 = T[9];
    const float a0 = S00;
    const float a1 = S10, b1 = S01;
    const float a2 = 2.0f * (S20 + S02) - S00;
    const float a3 = S20 - S02, b3 = 2.0f * S11;
    const float a4 = 3.0f * (S30 + S12) - 2.0f * S10;
    const float b4 = 3.0f * (S21 + S03) - 2.0f * S01;
    const float a5 = S30 - 3.0f * S12;
    const float b5 = 3.0f * S21 - S03;
    float* po = pooled + (size_t)b * 576 + rank * 192 + t;
    const float INV = 1.0f / 65536.0f;     // (1/256)^2 for the means
    po[0]   = (1.0f / PI_F) * sqrtf(a0 * a0 * INV + 1e-12f);
    po[32]  = (2.0f / PI_F) * sqrtf(fmaf(a1, a1, b1 * b1) * INV + 1e-12f);
    po[64]  = (3.0f / PI_F) * sqrtf(a2 * a2 * INV + 1e-12f);
    po[96]  = (3.0f / PI_F) * sqrtf(fmaf(a3, a3, b3 * b3) * INV + 1e-12f);
    po[128] = (4.0f / PI_F) * sqrtf(fmaf(a4, a4, b4 * b4) * INV + 1e-12f);
    po[160] = (4.0f / PI_F) * sqrtf(fmaf(a5, a5, b5 * b5) * INV + 1e-12f);
  }
}

// Kernel 2: BN stats, float4 edition (= round-14; unchanged).
__global__ __launch_bounds__(256) void bn_stats_kernel(const float* __restrict__ pooled,
                                                       const float* __restrict__ gamma,
                                                       const float* __restrict__ beta,
                                                       float* __restrict__ a,
                                                       float* __restrict__ c) {
  const int f0 = blockIdx.x * 4;           // 0,4,...,572
  const int t = threadIdx.x;               // 256
  const floatx4* __restrict__ p =
      reinterpret_cast<const floatx4*>(pooled + f0);   // row stride 144 float4
  floatx4 s = {0, 0, 0, 0}, q = {0, 0, 0, 0};
#pragma unroll
  for (int j = 0; j < 4; ++j) {
    const floatx4 v = p[(size_t)(t + 256 * j) * 144];
    s += v;
    q += v * v;
  }
#pragma unroll
  for (int cc = 0; cc < 4; ++cc) {
    s[cc] = red64(s[cc]);
    q[cc] = red64(q[cc]);
  }
  __shared__ float ls[4][8];
  const int w = t >> 6;
  if ((t & 63) == 0) {
#pragma unroll
    for (int cc = 0; cc < 4; ++cc) { ls[w][cc] = s[cc]; ls[w][4 + cc] = q[cc]; }
  }
  __syncthreads();
  if (t < 4) {                             // thread t -> feature f0+t
    float S = 0.0f, Q = 0.0f;
#pragma unroll
    for (int i = 0; i < 4; ++i) { S += ls[i][t]; Q += ls[i][4 + t]; }
    const float mean = S * (1.0f / 1024.0f);
    const float var = fmaf(-mean, mean, Q * (1.0f / 1024.0f));  // biased var
    const float istd = rsqrtf(var + 1e-5f);
    const float av = gamma[f0 + t] * istd;
    a[f0 + t] = av;
    c[f0 + t] = fmaf(-mean, av, beta[f0 + t]);
  }
}

// Kernel 3: head, 2 rows per wave with W/a/c held in registers.
// Load-instrs per 2 rows: 234 -> 126 (W read once per wave, not per row).
__global__ __launch_bounds__(64) void head_kernel(const float* __restrict__ pooled,
                                                  const float* __restrict__ a,
                                                  const float* __restrict__ c,
                                                  const float* __restrict__ Wl,
                                                  const float* __restrict__ bl,
                                                  float* __restrict__ out) {
  const int row0 = blockIdx.x * 2;   // 0,2,...,1022
  const int lane = threadIdx.x;      // 0..63

  // Per-lane W column block: w_[j][i] = Wl[i][lane+64j], plus a,c (loaded once).
  float w_[9][10];
  float av[9], cv[9];
#pragma unroll
  for (int j = 0; j < 9; ++j) {
    const int k = lane + 64 * j;
    av[j] = a[k];
    cv[j] = c[k];
#pragma unroll
    for (int i = 0; i < 10; ++i) w_[j][i] = Wl[i * 576 + k];
  }

  float acc[2][10];
#pragma unroll
  for (int r = 0; r < 2; ++r) {
    const float* pr = pooled + (size_t)(row0 + r) * 576;
#pragma unroll
    for (int i = 0; i < 10; ++i) acc[r][i] = 0.0f;
#pragma unroll
    for (int j = 0; j < 9; ++j) {
      const float z = fmaf(pr[lane + 64 * j], av[j], cv[j]);
#pragma unroll
      for (int i = 0; i < 10; ++i) acc[r][i] = fmaf(z, w_[j][i], acc[r][i]);
    }
  }
#pragma unroll
  for (int r = 0; r < 2; ++r)
#pragma unroll
    for (int i = 0; i < 10; ++i) acc[r][i] = red64(acc[r][i]);

  if (lane == 0) {
#pragma unroll
    for (int r = 0; r < 2; ++r) {
      float* o = out + (size_t)(row0 + r) * 10;
#pragma unroll
      for (int i = 0; i < 10; ++i) o[i] = acc[r][i] + bl[i];
    }
  }
}

extern "C" void kernel_launch(void* const* d_in, const int* in_sizes, int n_in,
                              void* d_out, int out_size, void* d_ws, size_t ws_size,
                              hipStream_t stream) {
  const float* x     = (const float*)d_in[0];
  const float* gamma = (const float*)d_in[1];
  const float* beta  = (const float*)d_in[2];
  const float* Wl    = (const float*)d_in[3];
  const float* bl    = (const float*)d_in[4];
  float* out = (float*)d_out;

  float* pooled = (float*)d_ws;            // 1024*576 floats
  float* a = pooled + 576 * 1024;          // 576 floats
  float* c = a + 576;                      // 576 floats

  zpool_kernel<<<3072, 256, 0, stream>>>(x, pooled);
  bn_stats_kernel<<<144, 256, 0, stream>>>(pooled, gamma, beta, a, c);
  head_kernel<<<512, 64, 0, stream>>>(pooled, a, c, Wl, bl, out);
}